// Round 1
// baseline (598.239 us; speedup 1.0000x reference)
//
#include <hip/hip_runtime.h>
#include <math.h>

#define D    6
#define S    128
#define H    128
#define WIN  16
#define BB   8
#define TT   513
#define NW   32      // (TT-1)/WIN
#define OUTD 10

// ---- device-global scratch (avoids any dependence on ws_size) ----
__device__ float g_Wt_v0[H * S];        // [k][r]  = W_v0[r][k]
__device__ float g_Wt_v1[H * H];        // [k][r]  = W_v1[r][k]
__device__ float g_Wt_v2[H * (D * S)];  // [a][jb] = W_v2[jb][a]
__device__ float g_lvl1[BB * NW * D];
__device__ float g_area[BB * NW * D * D];
__device__ float g_h0[BB * S];

__device__ __forceinline__ float sp(float x) {          // softplus
    return (x > 20.f) ? x : log1pf(expf(x));
}
__device__ __forceinline__ float sigm(float x) {        // softplus'
    return 1.f / (1.f + expf(-x));
}

// ---- K1: transpose the vector-field weights ----
__global__ void k_prep(const float* __restrict__ Wv0,
                       const float* __restrict__ Wv1,
                       const float* __restrict__ Wv2) {
    const int n0 = S * H, n1 = H * H, n2 = (D * S) * H;
    for (int i = blockIdx.x * blockDim.x + threadIdx.x; i < n0 + n1 + n2;
         i += gridDim.x * blockDim.x) {
        if (i < n0) {
            int r = i / H, k = i % H;
            g_Wt_v0[k * S + r] = Wv0[i];
        } else if (i < n0 + n1) {
            int t = i - n0; int r = t / H, k = t % H;
            g_Wt_v1[k * H + r] = Wv1[t];
        } else {
            int t = i - n0 - n1; int jb = t / H, a = t % H;
            g_Wt_v2[a * (D * S) + jb] = Wv2[t];
        }
    }
}

// ---- K2: windowed log-signature + init MLP (one block per batch) ----
__global__ __launch_bounds__(256) void k_sig(
        const float* __restrict__ x,
        const float* __restrict__ Wi0, const float* __restrict__ bi0,
        const float* __restrict__ Wi1, const float* __restrict__ bi1,
        const float* __restrict__ Wi2, const float* __restrict__ bi2) {
    const int b = blockIdx.x;
    const int tid = threadIdx.x;
    __shared__ float dxs[NW][WIN][D];
    __shared__ float cums[NW][WIN][D];
    __shared__ float ua[H], ub[H];

    const float* xb = x + (size_t)b * TT * D;

    if (tid < NW * D) {
        int w = tid / D, i = tid % D;
        float run = 0.f;
        float prev = xb[(w * WIN) * D + i];
        for (int k = 0; k < WIN; ++k) {
            float cur = xb[(w * WIN + k + 1) * D + i];
            float d = cur - prev; prev = cur;
            dxs[w][k][i] = d;
            cums[w][k][i] = run;
            run += d;
        }
        g_lvl1[(b * NW + w) * D + i] = run;
    }
    __syncthreads();
    for (int e = tid; e < NW * D * D; e += blockDim.x) {
        int w = e / (D * D); int rem = e % (D * D);
        int i = rem / D, j = rem % D;
        float s = 0.f;
        for (int k = 0; k < WIN; ++k)
            s += cums[w][k][i] * dxs[w][k][j] - cums[w][k][j] * dxs[w][k][i];
        g_area[(b * NW + w) * (D * D) + rem] = 0.5f * s;
    }
    // init MLP: h0 = Wi2 sp(Wi1 sp(Wi0 x0 + bi0) + bi1) + bi2
    if (tid < H) {
        float z = bi0[tid];
        for (int k = 0; k < D; ++k) z += Wi0[tid * D + k] * xb[k];
        ua[tid] = sp(z);
    }
    __syncthreads();
    if (tid < H) {
        float z = bi1[tid];
        for (int k = 0; k < H; ++k) z += Wi1[tid * H + k] * ua[k];
        ub[tid] = sp(z);
    }
    __syncthreads();
    if (tid < H) {
        float z = bi2[tid];
        for (int k = 0; k < H; ++k) z += Wi2[tid * H + k] * ub[k];
        g_h0[b * S + tid] = z;
    }
}

// ---- K3: the sequential log-ODE scan (one block per batch) + readout ----
__global__ __launch_bounds__(768) void k_scan(
        const float* __restrict__ bv0, const float* __restrict__ bv1,
        const float* __restrict__ bv2,
        const float* __restrict__ Wr,  const float* __restrict__ br,
        float* __restrict__ out) {
    const int b = blockIdx.x;
    const int tid = threadIdx.x;
    const int r = tid & (S - 1);   // 0..127
    const int g = tid >> 7;        // 0..5  (direction / j-block)

    __shared__ float h[S], sg1[S], sg2[S], u1[S], u2[S];
    __shared__ float V[D * S], T1p[D * S], T2p[D * S], G[D * S], P[D * S];
    __shared__ float l1s[D], ars[D * D];
    __shared__ float hist[NW + 1][S];

    if (tid < S) {
        float hv = g_h0[b * S + tid];
        h[tid] = hv;
        hist[0][tid] = hv;
    }
    __syncthreads();

    for (int t = 0; t < NW; ++t) {
        if (tid < D)     l1s[tid] = g_lvl1[(b * NW + t) * D + tid];
        if (tid < D * D) ars[tid] = g_area[(b * NW + t) * (D * D) + tid];
        // S1: z1 = Wv0 h + bv0
        if (tid < S) {
            float z = bv0[tid];
            #pragma unroll 8
            for (int k = 0; k < H; ++k) z += g_Wt_v0[k * S + tid] * h[k];
            u1[tid] = sp(z); sg1[tid] = sigm(z);
        }
        __syncthreads();
        // S2: z2 = Wv1 u1 + bv1
        if (tid < S) {
            float z = bv1[tid];
            #pragma unroll 8
            for (int k = 0; k < H; ++k) z += g_Wt_v1[k * S + tid] * u1[k];
            u2[tid] = sp(z); sg2[tid] = sigm(z);
        }
        __syncthreads();
        // S3: z3 = Wv2 u2 + bv2; V = tanh(z3)   (768 rows)
        {
            float z = bv2[tid];
            #pragma unroll 8
            for (int a = 0; a < H; ++a) z += g_Wt_v2[a * (D * S) + tid] * u2[a];
            V[tid] = tanhf(z);
        }
        __syncthreads();
        // S4: T1' = sigma(z1) .* (Wv0 V_i)   for all 6 directions at once
        {
            float z = 0.f;
            #pragma unroll 8
            for (int k = 0; k < H; ++k) z += g_Wt_v0[k * S + r] * V[g * S + k];
            T1p[g * S + r] = sg1[r] * z;
        }
        __syncthreads();
        // S5: T2' = sigma(z2) .* (Wv1 T1')
        {
            float z = 0.f;
            #pragma unroll 8
            for (int k = 0; k < H; ++k) z += g_Wt_v1[k * S + r] * T1p[g * S + k];
            T2p[g * S + r] = sg2[r] * z;
        }
        __syncthreads();
        // S6a: fold Levy area early: G[j][a] = sum_i T2'[a,i] * area[i][j]
        {
            float z = 0.f;
            #pragma unroll
            for (int i = 0; i < D; ++i) z += T2p[i * S + r] * ars[i * D + g];
            G[g * S + r] = z;
        }
        __syncthreads();
        // S6b: P[jb] = (1-V^2) .* (Wv2 G_j)[jb]
        {
            float z = 0.f;
            #pragma unroll 8
            for (int a = 0; a < H; ++a) z += g_Wt_v2[a * (D * S) + tid] * G[g * S + a];
            float v = V[tid];
            P[tid] = (1.f - v * v) * z;
        }
        __syncthreads();
        // S7: h update
        if (tid < S) {
            float hn = h[tid];
            #pragma unroll
            for (int i = 0; i < D; ++i) hn += l1s[i] * V[i * S + tid];
            #pragma unroll
            for (int j = 0; j < D; ++j) hn += P[j * S + tid];
            h[tid] = hn;
            hist[t + 1][tid] = hn;
        }
        __syncthreads();
    }

    // readout: out[b, t, o] = hist[t] . Wr[o] + br[o]
    for (int e = tid; e < (NW + 1) * OUTD; e += blockDim.x) {
        int tt = e / OUTD, o = e % OUTD;
        float z = br[o];
        for (int s = 0; s < S; ++s) z += hist[tt][s] * Wr[o * S + s];
        out[(b * (NW + 1) + tt) * OUTD + o] = z;
    }
}

extern "C" void kernel_launch(void* const* d_in, const int* in_sizes, int n_in,
                              void* d_out, int out_size, void* d_ws, size_t ws_size,
                              hipStream_t stream) {
    const float* x   = (const float*)d_in[0];
    const float* Wi0 = (const float*)d_in[1];
    const float* bi0 = (const float*)d_in[2];
    const float* Wi1 = (const float*)d_in[3];
    const float* bi1 = (const float*)d_in[4];
    const float* Wi2 = (const float*)d_in[5];
    const float* bi2 = (const float*)d_in[6];
    const float* Wv0 = (const float*)d_in[7];
    const float* bv0 = (const float*)d_in[8];
    const float* Wv1 = (const float*)d_in[9];
    const float* bv1 = (const float*)d_in[10];
    const float* Wv2 = (const float*)d_in[11];
    const float* bv2 = (const float*)d_in[12];
    const float* Wr  = (const float*)d_in[13];
    const float* br  = (const float*)d_in[14];
    float* out = (float*)d_out;

    hipLaunchKernelGGL(k_prep, dim3(128), dim3(256), 0, stream, Wv0, Wv1, Wv2);
    hipLaunchKernelGGL(k_sig,  dim3(BB),  dim3(256), 0, stream,
                       x, Wi0, bi0, Wi1, bi1, Wi2, bi2);
    hipLaunchKernelGGL(k_scan, dim3(BB),  dim3(768), 0, stream,
                       bv0, bv1, bv2, Wr, br, out);
}

// Round 2
// 497.526 us; speedup vs baseline: 1.2024x; 1.2024x over previous
//
#include <hip/hip_runtime.h>
#include <math.h>

#define D    6
#define S    128
#define H    128
#define WIN  16
#define BB   8
#define TT   513
#define NW   32
#define OUTD 10
#define NTHR 768

// ---- device-global scratch ----
__device__ float g_Wt_v0[H * S];        // [k][r]  = W_v0[r][k]
__device__ float g_Wt_v1[H * H];        // [k][r]  = W_v1[r][k]
__device__ float g_Wt_v2[H * (D * S)];  // [a][jb] = W_v2[jb][a]
__device__ float g_lvl1[BB * NW * D];
__device__ float g_area[BB * NW * D * D];
__device__ float g_h0[BB * S];
__device__ float g_hist[BB * (NW + 1) * S];

__device__ __forceinline__ float sp(float x) {
    return (x > 20.f) ? x : log1pf(expf(x));
}
__device__ __forceinline__ float sigm(float x) {
    return 1.f / (1.f + expf(-x));
}

// ---- K1: transpose weights ----
__global__ void k_prep(const float* __restrict__ Wv0,
                       const float* __restrict__ Wv1,
                       const float* __restrict__ Wv2) {
    const int n0 = S * H, n1 = H * H, n2 = (D * S) * H;
    for (int i = blockIdx.x * blockDim.x + threadIdx.x; i < n0 + n1 + n2;
         i += gridDim.x * blockDim.x) {
        if (i < n0) {
            int r = i / H, k = i % H;
            g_Wt_v0[k * S + r] = Wv0[i];
        } else if (i < n0 + n1) {
            int t = i - n0; int r = t / H, k = t % H;
            g_Wt_v1[k * H + r] = Wv1[t];
        } else {
            int t = i - n0 - n1; int jb = t / H, a = t % H;
            g_Wt_v2[a * (D * S) + jb] = Wv2[t];
        }
    }
}

// ---- K2: windowed log-signature + init MLP ----
__global__ __launch_bounds__(256) void k_sig(
        const float* __restrict__ x,
        const float* __restrict__ Wi0, const float* __restrict__ bi0,
        const float* __restrict__ Wi1, const float* __restrict__ bi1,
        const float* __restrict__ Wi2, const float* __restrict__ bi2) {
    const int b = blockIdx.x;
    const int tid = threadIdx.x;
    __shared__ float dxs[NW][WIN][D];
    __shared__ float cums[NW][WIN][D];
    __shared__ float ua[H], ub[H];

    const float* xb = x + (size_t)b * TT * D;

    if (tid < NW * D) {
        int w = tid / D, i = tid % D;
        float run = 0.f;
        float prev = xb[(w * WIN) * D + i];
        for (int k = 0; k < WIN; ++k) {
            float cur = xb[(w * WIN + k + 1) * D + i];
            float d = cur - prev; prev = cur;
            dxs[w][k][i] = d;
            cums[w][k][i] = run;
            run += d;
        }
        g_lvl1[(b * NW + w) * D + i] = run;
    }
    __syncthreads();
    for (int e = tid; e < NW * D * D; e += blockDim.x) {
        int w = e / (D * D); int rem = e % (D * D);
        int i = rem / D, j = rem % D;
        float s = 0.f;
        for (int k = 0; k < WIN; ++k)
            s += cums[w][k][i] * dxs[w][k][j] - cums[w][k][j] * dxs[w][k][i];
        g_area[(b * NW + w) * (D * D) + rem] = 0.5f * s;
    }
    if (tid < H) {
        float z = bi0[tid];
        for (int k = 0; k < D; ++k) z += Wi0[tid * D + k] * xb[k];
        ua[tid] = sp(z);
    }
    __syncthreads();
    if (tid < H) {
        float z = bi1[tid];
        for (int k = 0; k < H; ++k) z += Wi1[tid * H + k] * ua[k];
        ub[tid] = sp(z);
    }
    __syncthreads();
    if (tid < H) {
        float z = bi2[tid];
        for (int k = 0; k < H; ++k) z += Wi2[tid * H + k] * ub[k];
        g_h0[b * S + tid] = z;
    }
}

// ---- LDS layout (float offsets) ----
#define O_W0  0          // [128 k][128 r] fp32
#define O_W1  16384
#define O_PS  32768      // psum [6 c][6 j][128 r]
#define O_V   37376      // [6][128]
#define O_U   38144      // tangents U / T2p (aliased)
#define O_T1  38912
#define O_H   39680      // h double buffer [2][128]
#define O_U1  39936
#define O_SG1 40064
#define O_U2  40192
#define O_SG2 40320
#define O_B0  40448
#define O_B1  40576
#define O_L1  40704
#define O_AR  40710
#define SMTOT 40746     // 162,984 B <= 160 KiB

// ---- K3: the scan. 768 thr/block; thread = g*128 + r; owns Wv2 row tid ----
__global__ __launch_bounds__(768) void k_scan(
        const float* __restrict__ bv0, const float* __restrict__ bv1,
        const float* __restrict__ bv2) {
    __shared__ float sm[SMTOT];
    const int b = blockIdx.x, tid = threadIdx.x;
    const int r = tid & 127, g = tid >> 7;

    // stage Wv0/Wv1 to LDS
    {
        float4* w0 = (float4*)(sm + O_W0); const float4* s0 = (const float4*)g_Wt_v0;
        float4* w1 = (float4*)(sm + O_W1); const float4* s1 = (const float4*)g_Wt_v1;
        for (int i = tid; i < 4096; i += NTHR) { w0[i] = s0[i]; w1[i] = s1[i]; }
    }
    // own Wv2 row in registers
    float w2r[128];
    #pragma unroll
    for (int a = 0; a < 128; ++a) w2r[a] = g_Wt_v2[a * 768 + tid];
    const float b2 = bv2[tid];
    if (tid < 128) {
        sm[O_B0 + tid] = bv0[tid]; sm[O_B1 + tid] = bv1[tid];
        float h0v = g_h0[b * 128 + tid];
        sm[O_H + tid] = h0v;
        g_hist[(b * (NW + 1)) * 128 + tid] = h0v;
    }
    __syncthreads();

    // k-quad chunks: 32 quads over 6 groups: sizes {6,6,5,5,5,5}
    const int q0 = (g < 2) ? 6 * g : 12 + 5 * (g - 2);
    const int q1 = q0 + ((g < 2) ? 6 : 5);

    int p = 0;
    for (int t = 0; t < NW; ++t) {
        if (tid >= 704) {
            int q = tid - 704;
            if (q < 6)       sm[O_L1 + q]     = g_lvl1[(b * NW + t) * D + q];
            else if (q < 42) sm[O_AR + q - 6] = g_area[(b * NW + t) * (D * D) + q - 6];
        }
        // S1: psum of Wv0 . h
        {
            float acc = 0.f;
            for (int q = q0; q < q1; ++q) {
                int k = 4 * q;
                float w0 = sm[O_W0 + (k+0) * 128 + r];
                float w1 = sm[O_W0 + (k+1) * 128 + r];
                float w2 = sm[O_W0 + (k+2) * 128 + r];
                float w3 = sm[O_W0 + (k+3) * 128 + r];
                float4 xx = *(const float4*)&sm[O_H + p * 128 + k];
                acc = fmaf(w0, xx.x, fmaf(w1, xx.y, fmaf(w2, xx.z, fmaf(w3, xx.w, acc))));
            }
            sm[O_PS + ((g * 6) << 7) + r] = acc;
        }
        __syncthreads();
        if (tid < 128) {
            float z = sm[O_B0 + tid];
            #pragma unroll
            for (int c = 0; c < 6; ++c) z += sm[O_PS + ((c * 6) << 7) + tid];
            sm[O_U1 + tid] = sp(z); sm[O_SG1 + tid] = sigm(z);
        }
        __syncthreads();
        // S2: psum of Wv1 . u1
        {
            float acc = 0.f;
            for (int q = q0; q < q1; ++q) {
                int k = 4 * q;
                float w0 = sm[O_W1 + (k+0) * 128 + r];
                float w1 = sm[O_W1 + (k+1) * 128 + r];
                float w2 = sm[O_W1 + (k+2) * 128 + r];
                float w3 = sm[O_W1 + (k+3) * 128 + r];
                float4 xx = *(const float4*)&sm[O_U1 + k];
                acc = fmaf(w0, xx.x, fmaf(w1, xx.y, fmaf(w2, xx.z, fmaf(w3, xx.w, acc))));
            }
            sm[O_PS + ((g * 6) << 7) + r] = acc;
        }
        __syncthreads();
        if (tid < 128) {
            float z = sm[O_B1 + tid];
            #pragma unroll
            for (int c = 0; c < 6; ++c) z += sm[O_PS + ((c * 6) << 7) + tid];
            sm[O_U2 + tid] = sp(z); sm[O_SG2 + tid] = sigm(z);
        }
        __syncthreads();
        // S3: V = tanh(Wv2 u2 + bv2), row per thread from registers
        float tp;
        {
            float z0 = 0, z1 = 0, z2 = 0, z3 = 0;
            const float4* uu4 = (const float4*)&sm[O_U2];
            #pragma unroll
            for (int a4 = 0; a4 < 32; ++a4) {
                float4 uu = uu4[a4];
                z0 = fmaf(w2r[4*a4+0], uu.x, z0);
                z1 = fmaf(w2r[4*a4+1], uu.y, z1);
                z2 = fmaf(w2r[4*a4+2], uu.z, z2);
                z3 = fmaf(w2r[4*a4+3], uu.w, z3);
            }
            float v = tanhf(b2 + ((z0 + z1) + (z2 + z3)));
            sm[O_V + tid] = v; tp = 1.f - v * v;
        }
        __syncthreads();
        // UF: tangents U_j = sum_i area[i][j] V_i ; plus h-next init (+lvl1 term)
        {
            float u = 0.f;
            #pragma unroll
            for (int i = 0; i < 6; ++i) u = fmaf(sm[O_AR + i * 6 + g], sm[O_V + i * 128 + r], u);
            sm[O_U + g * 128 + r] = u;
            if (tid < 128) {
                float x = sm[O_H + p * 128 + tid];
                #pragma unroll
                for (int i = 0; i < 6; ++i) x = fmaf(sm[O_L1 + i], sm[O_V + i * 128 + tid], x);
                sm[O_H + (p ^ 1) * 128 + tid] = x;
            }
        }
        __syncthreads();
        // S4: JVP layer 1 for 6 tangents — k-split psum
        {
            float acc[6] = {0, 0, 0, 0, 0, 0};
            for (int q = q0; q < q1; ++q) {
                int k = 4 * q;
                float w0 = sm[O_W0 + (k+0) * 128 + r];
                float w1 = sm[O_W0 + (k+1) * 128 + r];
                float w2 = sm[O_W0 + (k+2) * 128 + r];
                float w3 = sm[O_W0 + (k+3) * 128 + r];
                #pragma unroll
                for (int j = 0; j < 6; ++j) {
                    float4 xx = *(const float4*)&sm[O_U + j * 128 + k];
                    acc[j] = fmaf(w0, xx.x, fmaf(w1, xx.y, fmaf(w2, xx.z, fmaf(w3, xx.w, acc[j]))));
                }
            }
            #pragma unroll
            for (int j = 0; j < 6; ++j) sm[O_PS + ((g * 6 + j) << 7) + r] = acc[j];
        }
        __syncthreads();
        // S4c: T1 = sg1 .* sum_c psum
        {
            float s = 0.f;
            #pragma unroll
            for (int c = 0; c < 6; ++c) s += sm[O_PS + ((c * 6 + g) << 7) + r];
            sm[O_T1 + g * 128 + r] = sm[O_SG1 + r] * s;
        }
        __syncthreads();
        // S5: JVP layer 2
        {
            float acc[6] = {0, 0, 0, 0, 0, 0};
            for (int q = q0; q < q1; ++q) {
                int k = 4 * q;
                float w0 = sm[O_W1 + (k+0) * 128 + r];
                float w1 = sm[O_W1 + (k+1) * 128 + r];
                float w2 = sm[O_W1 + (k+2) * 128 + r];
                float w3 = sm[O_W1 + (k+3) * 128 + r];
                #pragma unroll
                for (int j = 0; j < 6; ++j) {
                    float4 xx = *(const float4*)&sm[O_T1 + j * 128 + k];
                    acc[j] = fmaf(w0, xx.x, fmaf(w1, xx.y, fmaf(w2, xx.z, fmaf(w3, xx.w, acc[j]))));
                }
            }
            #pragma unroll
            for (int j = 0; j < 6; ++j) sm[O_PS + ((g * 6 + j) << 7) + r] = acc[j];
        }
        __syncthreads();
        // S5c: T2p (into U) = sg2 .* sum_c psum
        {
            float s = 0.f;
            #pragma unroll
            for (int c = 0; c < 6; ++c) s += sm[O_PS + ((c * 6 + g) << 7) + r];
            sm[O_U + g * 128 + r] = sm[O_SG2 + r] * s;
        }
        __syncthreads();
        // S6b: bracket term, own row: tp * (Wv2_row . T2p_g)
        {
            float z0 = 0, z1 = 0, z2 = 0, z3 = 0;
            const float4* t4 = (const float4*)&sm[O_U + g * 128];
            #pragma unroll
            for (int a4 = 0; a4 < 32; ++a4) {
                float4 uu = t4[a4];
                z0 = fmaf(w2r[4*a4+0], uu.x, z0);
                z1 = fmaf(w2r[4*a4+1], uu.y, z1);
                z2 = fmaf(w2r[4*a4+2], uu.z, z2);
                z3 = fmaf(w2r[4*a4+3], uu.w, z3);
            }
            sm[O_PS + (g << 7) + r] = tp * ((z0 + z1) + (z2 + z3));
        }
        __syncthreads();
        // final: h_next += sum_j bracket_j ; write hist
        if (tid < 128) {
            float x = sm[O_H + (p ^ 1) * 128 + tid];
            #pragma unroll
            for (int j = 0; j < 6; ++j) x += sm[O_PS + (j << 7) + tid];
            sm[O_H + (p ^ 1) * 128 + tid] = x;
            g_hist[(b * (NW + 1) + t + 1) * 128 + tid] = x;
        }
        p ^= 1;
        __syncthreads();
    }
}

// ---- K4: readout ----
__global__ __launch_bounds__(384) void k_read(const float* __restrict__ Wr,
                                              const float* __restrict__ br,
                                              float* __restrict__ out) {
    const int b = blockIdx.x, e = threadIdx.x;
    if (e < (NW + 1) * OUTD) {
        int t = e / OUTD, o = e % OUTD;
        float z = br[o];
        const float4* hrow = (const float4*)&g_hist[(b * (NW + 1) + t) * 128];
        const float4* wrow = (const float4*)&Wr[o * 128];
        float z0 = 0, z1 = 0, z2 = 0, z3 = 0;
        #pragma unroll 8
        for (int s4 = 0; s4 < 32; ++s4) {
            float4 hv = hrow[s4]; float4 wv = wrow[s4];
            z0 = fmaf(hv.x, wv.x, z0); z1 = fmaf(hv.y, wv.y, z1);
            z2 = fmaf(hv.z, wv.z, z2); z3 = fmaf(hv.w, wv.w, z3);
        }
        out[(b * (NW + 1) + t) * OUTD + o] = z + ((z0 + z1) + (z2 + z3));
    }
}

extern "C" void kernel_launch(void* const* d_in, const int* in_sizes, int n_in,
                              void* d_out, int out_size, void* d_ws, size_t ws_size,
                              hipStream_t stream) {
    const float* x   = (const float*)d_in[0];
    const float* Wi0 = (const float*)d_in[1];
    const float* bi0 = (const float*)d_in[2];
    const float* Wi1 = (const float*)d_in[3];
    const float* bi1 = (const float*)d_in[4];
    const float* Wi2 = (const float*)d_in[5];
    const float* bi2 = (const float*)d_in[6];
    const float* Wv0 = (const float*)d_in[7];
    const float* bv0 = (const float*)d_in[8];
    const float* Wv1 = (const float*)d_in[9];
    const float* bv1 = (const float*)d_in[10];
    const float* Wv2 = (const float*)d_in[11];
    const float* bv2 = (const float*)d_in[12];
    const float* Wr  = (const float*)d_in[13];
    const float* br  = (const float*)d_in[14];
    float* out = (float*)d_out;

    hipLaunchKernelGGL(k_prep, dim3(128), dim3(256), 0, stream, Wv0, Wv1, Wv2);
    hipLaunchKernelGGL(k_sig,  dim3(BB),  dim3(256), 0, stream,
                       x, Wi0, bi0, Wi1, bi1, Wi2, bi2);
    hipLaunchKernelGGL(k_scan, dim3(BB),  dim3(768), 0, stream, bv0, bv1, bv2);
    hipLaunchKernelGGL(k_read, dim3(BB),  dim3(384), 0, stream, Wr, br, out);
}